// Round 1
// baseline (208.121 us; speedup 1.0000x reference)
//
#include <hip/hip_runtime.h>
#include <math.h>

#define HID 512
#define PPB 32              // points per block: 2 p-streams of 16
#define SLAB 512            // halfs per slab: 16 p x 32 k, 1 KB, lane-linear

typedef __attribute__((ext_vector_type(8))) _Float16 half8;   // 4 VGPRs, MFMA frag
typedef __attribute__((ext_vector_type(4))) _Float16 half4;
typedef __attribute__((ext_vector_type(4))) float f32x4;

static __device__ __forceinline__ float fast_tanh(float x) {
    float e = __expf(2.f * x);
    return 1.f - 2.f / (e + 1.f);
}

// ---------------------------------------------------------------------------
// Slab element order (lane-linear): element (p_local, k_local=quad*8+e) sits
// at halfs-offset lane*8+e, lane = quad*16 + p_local. One wave b128 access at
// lane*8 = contiguous 1 KB: conflict-free in LDS, coalesced in global.
// A slabs: index (s*2 + ph)*16 + kb   (ph = stream, kb = k/32). 128 KB total.
// W slabs: index jb*16 + kb           (jb = j/16). 512 KB per layer.
// ---------------------------------------------------------------------------

__global__ __launch_bounds__(256) void prep_wt(
    const float* __restrict__ W1, const float* __restrict__ W2,
    _Float16* __restrict__ W1h, _Float16* __restrict__ W2h,
    unsigned* __restrict__ counter)
{
    if (blockIdx.x == 0 && threadIdx.x == 0) *counter = 0u;   // reset per replay
    __shared__ float T[64][65];
    int b = blockIdx.x;
    const float* W = (b < 64) ? W1 : W2;
    _Float16* Wh   = (b < 64) ? W1h : W2h;
    int tb = b & 63;
    int jbG = tb >> 3, kbG = tb & 7;
    int j0 = jbG * 64, k0 = kbG * 64;
    int t = threadIdx.x;
    #pragma unroll
    for (int r = 0; r < 16; ++r) {
        int kl = r * 4 + (t >> 6);
        int jl = t & 63;
        T[kl][jl] = W[(size_t)(k0 + kl) * HID + j0 + jl];   // coalesced
    }
    __syncthreads();
    int ljb = t >> 6;                  // local 16-j group (0..3)
    int l15 = (t >> 2) & 15;           // j within group
    int quad = t & 3;                  // k octet
    #pragma unroll
    for (int lkb = 0; lkb < 2; ++lkb) {
        half8 v;
        #pragma unroll
        for (int k8 = 0; k8 < 8; ++k8)
            v[k8] = (_Float16)T[lkb * 32 + quad * 8 + k8][ljb * 16 + l15];
        size_t out = (size_t)((jbG * 4 + ljb) * 16 + (kbG * 2 + lkb)) * SLAB
                   + (quad * 16 + l15) * 8;
        *(half8*)(Wh + out) = v;
    }
}

// ---------------------------------------------------------------------------
// Epilogue for ONE 16-j group (jt) of stream PHE. MODE: 1 = all 4 states,
// 2 = h and S only (last hidden layer). Reads acc of the *previous* phase.
// ---------------------------------------------------------------------------
template<int PHE, int MODE>
static __device__ __forceinline__ void epi_one(
    int jt, const f32x4 (&accE)[4][2], const float* __restrict__ biasE,
    _Float16* Als, int wv, int lane)
{
    const int l15 = lane & 15, quad = lane >> 4;
    const int jbase = wv * 32 + jt * 16 + quad * 4;
    const int qo = jt * 2 + (quad >> 1);        // (jbase&31)>>3
    const int e0 = (quad & 1) * 4;              // jbase&7
    f32x4 bv = *(const f32x4*)&biasE[jbase];
    half4 vh, vt1, vt2, vS;
    #pragma unroll
    for (int r = 0; r < 4; ++r) {
        float a  = fast_tanh(accE[0][jt][r] + bv[r]);
        float g  = 1.f - a * a;
        float z1 = accE[1][jt][r];
        float z2 = accE[2][jt][r];
        vh[r] = (_Float16)a;
        if constexpr (MODE == 1) {
            vt1[r] = (_Float16)(g * z1);
            vt2[r] = (_Float16)(g * z2);
        }
        vS[r] = (_Float16)(g * accE[3][jt][r] - 2.f * a * g * (z1 * z1 + z2 * z2));
    }
    const int ooff = (qo * 16 + l15) * 8 + e0;
    *(half4*)(Als + ((0 * 2 + PHE) * 16 + wv) * SLAB + ooff) = vh;
    if constexpr (MODE == 1) {
        *(half4*)(Als + ((1 * 2 + PHE) * 16 + wv) * SLAB + ooff) = vt1;
        *(half4*)(Als + ((2 * 2 + PHE) * 16 + wv) * SLAB + ooff) = vt2;
    }
    *(half4*)(Als + ((3 * 2 + PHE) * 16 + wv) * SLAB + ooff) = vS;
}

// ---------------------------------------------------------------------------
// One pipeline phase: MFMA sweep for stream PH (acc += W * Als[PH]) with the
// epilogue of stream PHE (previous phase's acc) interleaved into the k-loop.
// MODE=0: no epilogue. Barriers live OUTSIDE this function.
// ---------------------------------------------------------------------------
template<int PH, int PHE, int MODE>
static __device__ __forceinline__ void layer_phase(
    const _Float16* __restrict__ Wh, const float* __restrict__ biasE,
    _Float16* Als, int wv, int lane,
    f32x4 (&acc)[4][2], const f32x4 (&accE)[4][2])
{
    const int jb0 = wv * 2;                 // first 16-j W slab index
    const int loff = lane * 8;              // lane-linear frag offset (halfs)

    #pragma unroll
    for (int s = 0; s < 4; ++s)
        #pragma unroll
        for (int jt = 0; jt < 2; ++jt) acc[s][jt] = (f32x4)0.f;

    half8 wA[2], wB[2];
    #pragma unroll
    for (int jt = 0; jt < 2; ++jt)
        wA[jt] = *(const half8*)(Wh + (size_t)((jb0 + jt) * 16) * SLAB + loff);

    auto iter = [&](int kb, half8 (&wc)[2], half8 (&wn)[2]) {
        if (kb < 15) {
            #pragma unroll
            for (int jt = 0; jt < 2; ++jt)
                wn[jt] = *(const half8*)(Wh + (size_t)((jb0 + jt) * 16 + kb + 1) * SLAB + loff);
        }
        half8 a[4];
        #pragma unroll
        for (int s = 0; s < 4; ++s)
            a[s] = *(const half8*)(Als + ((s * 2 + PH) * 16 + kb) * SLAB + loff);
        #pragma unroll
        for (int s = 0; s < 4; ++s)
            #pragma unroll
            for (int jt = 0; jt < 2; ++jt)
                acc[s][jt] = __builtin_amdgcn_mfma_f32_16x16x32_f16(
                    wc[jt], a[s], acc[s][jt], 0, 0, 0);
    };

    iter(0, wA, wB);
    iter(1, wB, wA);
    iter(2, wA, wB);
    if constexpr (MODE != 0) epi_one<PHE, MODE>(0, accE, biasE, Als, wv, lane);
    iter(3, wB, wA);
    iter(4, wA, wB);
    iter(5, wB, wA);
    iter(6, wA, wB);
    iter(7, wB, wA);
    iter(8, wA, wB);
    if constexpr (MODE != 0) epi_one<PHE, MODE>(1, accE, biasE, Als, wv, lane);
    iter(9, wB, wA);
    iter(10, wA, wB);
    iter(11, wB, wA);
    iter(12, wA, wB);
    iter(13, wB, wA);
    iter(14, wA, wB);
    iter(15, wB, wA);
}

// ---------------------------------------------------------------------------
// Layer-0 init for one stream (VALU + LDS writes; overlaps stream0's L1 MFMA)
// ---------------------------------------------------------------------------
static __device__ __forceinline__ void init_half(
    int ph, const float* __restrict__ x_int, const float* __restrict__ x_bnd,
    const float* __restrict__ W0, const float* __restrict__ b0,
    _Float16* Als, int wv, int lane, int p0, int NI, int NT)
{
    const int l15 = lane & 15, quad = lane >> 4;
    const int p = ph * 16 + l15;
    int gp = p0 + p;
    int gpc = (gp >= NT) ? 0 : gp;
    float xx, yy;
    if (gpc < NI) { xx = x_int[2 * gpc];        yy = x_int[2 * gpc + 1]; }
    else          { xx = x_bnd[2 * (gpc - NI)]; yy = x_bnd[2 * (gpc - NI) + 1]; }
    const int k = wv * 32 + quad * 8;
    f32x4 w0a = *(const f32x4*)&W0[k],       w0b = *(const f32x4*)&W0[k + 4];
    f32x4 w1a = *(const f32x4*)&W0[HID + k], w1b = *(const f32x4*)&W0[HID + k + 4];
    f32x4 b0a = *(const f32x4*)&b0[k],       b0b = *(const f32x4*)&b0[k + 4];
    half8 vh, vt1, vt2, vS;
    #pragma unroll
    for (int e = 0; e < 8; ++e) {
        float w0i = (e < 4) ? w0a[e] : w0b[e - 4];
        float w1i = (e < 4) ? w1a[e] : w1b[e - 4];
        float bbi = (e < 4) ? b0a[e] : b0b[e - 4];
        float a = fast_tanh(xx * w0i + yy * w1i + bbi);
        float g = 1.f - a * a;
        vh[e]  = (_Float16)a;
        vt1[e] = (_Float16)(g * w0i);
        vt2[e] = (_Float16)(g * w1i);
        vS[e]  = (_Float16)(-2.f * a * g * (w0i * w0i + w1i * w1i));
    }
    const int off = lane * 8;
    *(half8*)(Als + ((0 * 2 + ph) * 16 + wv) * SLAB + off) = vh;
    *(half8*)(Als + ((1 * 2 + ph) * 16 + wv) * SLAB + off) = vt1;
    *(half8*)(Als + ((2 * 2 + ph) * 16 + wv) * SLAB + off) = vt2;
    *(half8*)(Als + ((3 * 2 + ph) * 16 + wv) * SLAB + off) = vS;
}

// ---------------------------------------------------------------------------
// Final W3 dot for one stream: u and lap partials per point into scU/scL
// ---------------------------------------------------------------------------
template<int PH>
static __device__ __forceinline__ void final_half(
    const float* __restrict__ W3, _Float16* Als, int wv, int lane,
    float (*scU)[32], float (*scL)[32])
{
    const int quad = lane >> 4;
    const int k = wv * 32 + quad * 8;
    f32x4 wa = *(const f32x4*)&W3[k], wb = *(const f32x4*)&W3[k + 4];
    half8 hh = *(const half8*)(Als + ((0 * 2 + PH) * 16 + wv) * SLAB + lane * 8);
    half8 ss = *(const half8*)(Als + ((3 * 2 + PH) * 16 + wv) * SLAB + lane * 8);
    float u = 0.f, lap = 0.f;
    #pragma unroll
    for (int e = 0; e < 4; ++e) {
        u   += (float)hh[e] * wa[e] + (float)hh[e + 4] * wb[e];
        lap += (float)ss[e] * wa[e] + (float)ss[e + 4] * wb[e];
    }
    // reduce over quad (lanes sharing l15): xor 16, 32
    u   += __shfl_xor(u, 16);   u   += __shfl_xor(u, 32);
    lap += __shfl_xor(lap, 16); lap += __shfl_xor(lap, 32);
    if (lane < 16) { scU[wv][PH * 16 + lane] = u; scL[wv][PH * 16 + lane] = lap; }
}

// ---------------------------------------------------------------------------
// Fused: 2-stream (p-half) software pipeline. Every barrier-phase mixes one
// stream's MFMA sweep with the other stream's VALU epilogue so the MFMA pipe
// never sits idle behind a pure-VALU phase. Last block folds in the final
// reduction (atomic counter), removing the pois_reduce launch.
// 32 pts/block, 1024 threads (16 waves), 1 block/CU -> 4 waves/SIMD.
// ---------------------------------------------------------------------------
__global__ __launch_bounds__(1024, 4) void pois_fused(
    const float* __restrict__ x_int, const float* __restrict__ x_bnd,
    const float* __restrict__ W0, const float* __restrict__ b0,
    const _Float16* __restrict__ W1h, const float* __restrict__ b1,
    const _Float16* __restrict__ W2h, const float* __restrict__ b2,
    const float* __restrict__ W3, const float* __restrict__ b3,
    float* __restrict__ partials, unsigned* __restrict__ counter,
    float* __restrict__ out, int NI, int NT, int nblk)
{
    __shared__ _Float16 Als[8 * 16 * SLAB];   // 128 KB
    __shared__ float scU[16][32], scL[16][32], sc[64];
    __shared__ float ri[4], rb[4];
    __shared__ int lastFlag;

    const int tid = threadIdx.x;
    const int wv = tid >> 6, lane = tid & 63;
    const int p0 = blockIdx.x * PPB;

    f32x4 accA[4][2], accB[4][2];             // [state][jt], one set per stream

    // P0: init stream 0
    init_half(0, x_int, x_bnd, W0, b0, Als, wv, lane, p0, NI, NT);
    __syncthreads();

    // P1: L1 mfma s0  ||  init s1      (writes s1 slabs, reads s0 slabs)
    layer_phase<0, 0, 0>(W1h, b1, Als, wv, lane, accA, accA);
    init_half(1, x_int, x_bnd, W0, b0, Als, wv, lane, p0, NI, NT);
    __syncthreads();

    // P2: L1 mfma s1  ||  epi L1 s0    (writes s0 slabs, reads s1 slabs)
    layer_phase<1, 0, 1>(W1h, b1, Als, wv, lane, accB, accA);
    __syncthreads();

    // P3: L2 mfma s0  ||  epi L1 s1
    layer_phase<0, 1, 1>(W2h, b1, Als, wv, lane, accA, accB);
    __syncthreads();

    // P4: L2 mfma s1  ||  epi L2 s0 (h,S only)
    layer_phase<1, 0, 2>(W2h, b2, Als, wv, lane, accB, accA);
    __syncthreads();

    // P5: epi L2 s1 (h,S only)  ||  final dot s0
    epi_one<1, 2>(0, accB, b2, Als, wv, lane);
    epi_one<1, 2>(1, accB, b2, Als, wv, lane);
    final_half<0>(W3, Als, wv, lane, scU, scL);
    __syncthreads();

    // P6: final dot s1
    final_half<1>(W3, Als, wv, lane, scU, scL);
    __syncthreads();

    // per-point losses
    if (tid < 32) {
        const int p = tid;
        float u = 0.f, lap = 0.f;
        #pragma unroll
        for (int w = 0; w < 16; ++w) { u += scU[w][p]; lap += scL[w][p]; }
        int gp = p0 + p;
        float vi = 0.f, vb = 0.f;
        if (gp < NI) {
            const float PIf = 3.14159265358979323846f;
            float xx = x_int[2 * gp], yy = x_int[2 * gp + 1];
            float sx = sinf(PIf * xx);
            float y2 = yy * yy;
            float sy = sinf(PIf * y2), cy = cosf(PIf * y2);
            float f = -PIf * PIf * (1.f + 4.f * y2) * sx * sy + 2.f * PIf * sx * cy;
            float r = lap - f;
            vi = r * r;
        } else if (gp < NT) {
            float uu = u + b3[0];
            vb = uu * uu;
        }
        sc[p * 2] = vi; sc[p * 2 + 1] = vb;
    }
    __syncthreads();
    if (tid == 0) {
        float svi = 0.f, svb = 0.f;
        #pragma unroll
        for (int p = 0; p < PPB; ++p) { svi += sc[p * 2]; svb += sc[p * 2 + 1]; }
        partials[blockIdx.x] = svi;
        partials[nblk + blockIdx.x] = svb;
        __threadfence();                              // release partials
        unsigned old = atomicAdd(counter, 1u);
        lastFlag = (old == (unsigned)(nblk - 1));
    }
    __syncthreads();

    // last arriving block: deterministic final reduction (same summation
    // order as the old pois_reduce kernel -> bitwise-identical result)
    if (lastFlag) {
        __threadfence();                              // acquire partials
        if (tid < 256) {
            float si = 0.f, sb = 0.f;
            for (int i = tid; i < nblk; i += 256) {
                si += partials[i];
                sb += partials[nblk + i];
            }
            #pragma unroll
            for (int off = 32; off > 0; off >>= 1) {
                si += __shfl_xor(si, off);
                sb += __shfl_xor(sb, off);
            }
            int w = tid >> 6;
            if ((tid & 63) == 0) { ri[w] = si; rb[w] = sb; }
        }
    }
    __syncthreads();
    if (lastFlag && tid == 0) {
        float inter = (ri[0] + ri[1] + ri[2] + ri[3]) / (float)NI;
        float bound = (rb[0] + rb[1] + rb[2] + rb[3]) / (float)(NT - NI);
        out[0] = 0.01f * inter + bound;   // ALPHA = 0.01
        out[1] = inter;
        out[2] = bound;
    }
}

// ---------------------------------------------------------------------------
extern "C" void kernel_launch(void* const* d_in, const int* in_sizes, int n_in,
                              void* d_out, int out_size, void* d_ws, size_t ws_size,
                              hipStream_t stream)
{
    const float* x_int = (const float*)d_in[0];
    const float* x_bnd = (const float*)d_in[1];
    const float* W0 = (const float*)d_in[2];
    const float* b0 = (const float*)d_in[3];
    const float* W1 = (const float*)d_in[4];
    const float* b1 = (const float*)d_in[5];
    const float* W2 = (const float*)d_in[6];
    const float* b2 = (const float*)d_in[7];
    const float* W3 = (const float*)d_in[8];
    const float* b3 = (const float*)d_in[9];

    int NI = in_sizes[0] / 2;    // 20000
    int NB = in_sizes[1] / 2;    // 800
    int NT = NI + NB;            // 20800
    int nblk = (NT + PPB - 1) / PPB;   // 650
    (void)NB;

    // ws: [partials 8KB][counter][pad to 16KB][W1h 512KB][W2h 512KB]
    float* partials = (float*)d_ws;
    unsigned* counter = (unsigned*)((char*)d_ws + 8192);
    _Float16* W1h = (_Float16*)((char*)d_ws + 16384);
    _Float16* W2h = W1h + 262144;

    prep_wt<<<128, 256, 0, stream>>>(W1, W2, W1h, W2h, counter);

    pois_fused<<<nblk, 1024, 0, stream>>>(
        x_int, x_bnd, W0, b0, W1h, b1, W2h, b2, W3, b3,
        partials, counter, (float*)d_out, NI, NT, nblk);
}

// Round 2
// 207.395 us; speedup vs baseline: 1.0035x; 1.0035x over previous
//
#include <hip/hip_runtime.h>
#include <math.h>

#define HID 512
#define PPB 16              // points per block (one 16-p MFMA column)
#define SLAB 512            // halfs per slab: 16 p x 32 k, 1 KB, lane-linear

typedef __attribute__((ext_vector_type(8))) _Float16 half8;   // 4 VGPRs, MFMA frag
typedef __attribute__((ext_vector_type(4))) _Float16 half4;
typedef __attribute__((ext_vector_type(4))) float f32x4;

static __device__ __forceinline__ float fast_tanh(float x) {
    float e = __expf(2.f * x);
    return 1.f - 2.f / (e + 1.f);
}

// ---------------------------------------------------------------------------
// Slab element order (lane-linear): element (p_local, k_local=quad*8+e) sits
// at halfs-offset lane*8+e, lane = quad*16 + p_local. One wave b128 access at
// lane*8 = contiguous 1 KB: conflict-free in LDS, coalesced in global.
// A slabs: index s*16 + kb   (s = state, kb = k/32). 64 KB total -> 2 blk/CU.
// W slabs: index jb*16 + kb  (jb = j/16). 512 KB per layer.
// ---------------------------------------------------------------------------

__global__ __launch_bounds__(256) void prep_wt(
    const float* __restrict__ W1, const float* __restrict__ W2,
    _Float16* __restrict__ W1h, _Float16* __restrict__ W2h,
    unsigned* __restrict__ counter)
{
    if (blockIdx.x == 0 && threadIdx.x == 0) *counter = 0u;   // reset per replay
    __shared__ float T[64][65];
    int b = blockIdx.x;
    const float* W = (b < 64) ? W1 : W2;
    _Float16* Wh   = (b < 64) ? W1h : W2h;
    int tb = b & 63;
    int jbG = tb >> 3, kbG = tb & 7;
    int j0 = jbG * 64, k0 = kbG * 64;
    int t = threadIdx.x;
    #pragma unroll
    for (int r = 0; r < 16; ++r) {
        int kl = r * 4 + (t >> 6);
        int jl = t & 63;
        T[kl][jl] = W[(size_t)(k0 + kl) * HID + j0 + jl];   // coalesced
    }
    __syncthreads();
    int ljb = t >> 6;                  // local 16-j group (0..3)
    int l15 = (t >> 2) & 15;           // j within group
    int quad = t & 3;                  // k octet
    #pragma unroll
    for (int lkb = 0; lkb < 2; ++lkb) {
        half8 v;
        #pragma unroll
        for (int k8 = 0; k8 < 8; ++k8)
            v[k8] = (_Float16)T[lkb * 32 + quad * 8 + k8][ljb * 16 + l15];
        size_t out = (size_t)((jbG * 4 + ljb) * 16 + (kbG * 2 + lkb)) * SLAB
                   + (quad * 16 + l15) * 8;
        *(half8*)(Wh + out) = v;
    }
}

// ---------------------------------------------------------------------------
// One hidden-layer pass. A (B-op) in LDS slabs; W (A-op) streamed from L2
// with ping-pong register prefetch. Wave wv (of 8) owns j in [64wv, 64wv+64)
// (4 W slabs of 16 j); 1 p-frag; 4 states. acc = 64 AGPR.
// Per kb-iter: 4 ds_read_b128 + 4 global loads + 16 MFMA.
// ---------------------------------------------------------------------------
template<bool FULL>
static __device__ __forceinline__ void layer_pass(
    const _Float16* __restrict__ Wh, const float* __restrict__ bias,
    _Float16* Als, int wv, int lane)
{
    const int l15 = lane & 15, quad = lane >> 4;
    const int jb0 = wv * 4;                 // first 16-j W slab index
    const int loff = lane * 8;              // lane-linear frag offset (halfs)

    f32x4 acc[4][4];                        // [state][jt]
    #pragma unroll
    for (int s = 0; s < 4; ++s)
        #pragma unroll
        for (int jt = 0; jt < 4; ++jt) acc[s][jt] = (f32x4)0.f;

    half8 wA[4], wB[4];
    #pragma unroll
    for (int jt = 0; jt < 4; ++jt)
        wA[jt] = *(const half8*)(Wh + (size_t)((jb0 + jt) * 16) * SLAB + loff);

    auto iter = [&](int kb, half8 (&wc)[4], half8 (&wn)[4]) {
        if (kb < 15) {
            #pragma unroll
            for (int jt = 0; jt < 4; ++jt)
                wn[jt] = *(const half8*)(Wh + (size_t)((jb0 + jt) * 16 + kb + 1) * SLAB + loff);
        }
        half8 a[4];
        #pragma unroll
        for (int s = 0; s < 4; ++s)
            a[s] = *(const half8*)(Als + (s * 16 + kb) * SLAB + loff);
        #pragma unroll
        for (int s = 0; s < 4; ++s)
            #pragma unroll
            for (int jt = 0; jt < 4; ++jt)
                acc[s][jt] = __builtin_amdgcn_mfma_f32_16x16x32_f16(
                    wc[jt], a[s], acc[s][jt], 0, 0, 0);
    };

    #pragma unroll
    for (int kb = 0; kb < 16; kb += 2) {
        iter(kb,     wA, wB);
        iter(kb + 1, wB, wA);
    }

    __syncthreads();   // all waves done reading Als; safe to overwrite

    // epilogue: D row m = jt*16+quad*4+r (j-offset jbase), col p = l15.
    // Next-layer slab for jbase is kb' = jbase>>5 = 2wv + (jt>>1);
    // k_local = (jt&1)*16 + quad*4 + r.
    #pragma unroll
    for (int jt = 0; jt < 4; ++jt) {
        const int jbase = wv * 64 + jt * 16 + quad * 4;
        const int kbp = wv * 2 + (jt >> 1);
        const int qo = (jt & 1) * 2 + (quad >> 1);
        const int e0 = (quad & 1) * 4;
        f32x4 bv = *(const f32x4*)&bias[jbase];
        half4 vh, vt1, vt2, vS;
        #pragma unroll
        for (int r = 0; r < 4; ++r) {
            float a  = fast_tanh(acc[0][jt][r] + bv[r]);
            float g  = 1.f - a * a;
            float z1 = acc[1][jt][r];
            float z2 = acc[2][jt][r];
            vh[r] = (_Float16)a;
            if (FULL) {
                vt1[r] = (_Float16)(g * z1);
                vt2[r] = (_Float16)(g * z2);
            }
            vS[r] = (_Float16)(g * acc[3][jt][r] - 2.f * a * g * (z1 * z1 + z2 * z2));
        }
        const int ooff = (qo * 16 + l15) * 8 + e0;
        *(half4*)(Als + (0 * 16 + kbp) * SLAB + ooff) = vh;
        if (FULL) {
            *(half4*)(Als + (1 * 16 + kbp) * SLAB + ooff) = vt1;
            *(half4*)(Als + (2 * 16 + kbp) * SLAB + ooff) = vt2;
        }
        *(half4*)(Als + (3 * 16 + kbp) * SLAB + ooff) = vS;
    }
    __syncthreads();   // Als(next layer) complete
}

// ---------------------------------------------------------------------------
// Fused: layer0 init -> L1 -> L2 -> final dot + loss partials + grid reduce.
// 16 pts/block, 512 threads (8 waves), 64 KB LDS -> 2 blocks/CU.
// Cross-block phase drift overlaps one block's epilogue with the other's
// MFMA sweep (no intra-block pipelining, no extra live acc state).
// ---------------------------------------------------------------------------
__global__ __launch_bounds__(512, 4) void pois_fused(
    const float* __restrict__ x_int, const float* __restrict__ x_bnd,
    const float* __restrict__ W0, const float* __restrict__ b0,
    const _Float16* __restrict__ W1h, const float* __restrict__ b1,
    const _Float16* __restrict__ W2h, const float* __restrict__ b2,
    const float* __restrict__ W3, const float* __restrict__ b3,
    float* __restrict__ partials, unsigned* __restrict__ counter,
    float* __restrict__ out, int NI, int NT, int nblk)
{
    __shared__ _Float16 Als[4 * 16 * SLAB];   // 64 KB
    __shared__ float scU[8][16], scL[8][16], sc[32];
    __shared__ float ri[4], rb[4];
    __shared__ int lastFlag;

    const int tid = threadIdx.x;
    const int wv = tid >> 6, lane = tid & 63;
    const int l15 = lane & 15, quad = lane >> 4;
    const int p0 = blockIdx.x * PPB;

    // ---- layer 0: wave wv fills slabs kb = 2wv, 2wv+1 ----
    {
        int gp = p0 + l15;
        int gpc = (gp >= NT) ? 0 : gp;
        float xx, yy;
        if (gpc < NI) { xx = x_int[2 * gpc];        yy = x_int[2 * gpc + 1]; }
        else          { xx = x_bnd[2 * (gpc - NI)]; yy = x_bnd[2 * (gpc - NI) + 1]; }
        #pragma unroll
        for (int t = 0; t < 2; ++t) {
            const int kb = wv * 2 + t;
            const int k = kb * 32 + quad * 8;
            f32x4 w0a = *(const f32x4*)&W0[k],       w0b = *(const f32x4*)&W0[k + 4];
            f32x4 w1a = *(const f32x4*)&W0[HID + k], w1b = *(const f32x4*)&W0[HID + k + 4];
            f32x4 b0a = *(const f32x4*)&b0[k],       b0b = *(const f32x4*)&b0[k + 4];
            half8 vh, vt1, vt2, vS;
            #pragma unroll
            for (int e = 0; e < 8; ++e) {
                float w0i = (e < 4) ? w0a[e] : w0b[e - 4];
                float w1i = (e < 4) ? w1a[e] : w1b[e - 4];
                float bbi = (e < 4) ? b0a[e] : b0b[e - 4];
                float a = fast_tanh(xx * w0i + yy * w1i + bbi);
                float g = 1.f - a * a;
                vh[e]  = (_Float16)a;
                vt1[e] = (_Float16)(g * w0i);
                vt2[e] = (_Float16)(g * w1i);
                vS[e]  = (_Float16)(-2.f * a * g * (w0i * w0i + w1i * w1i));
            }
            const int off = lane * 8;
            *(half8*)(Als + (0 * 16 + kb) * SLAB + off) = vh;
            *(half8*)(Als + (1 * 16 + kb) * SLAB + off) = vt1;
            *(half8*)(Als + (2 * 16 + kb) * SLAB + off) = vt2;
            *(half8*)(Als + (3 * 16 + kb) * SLAB + off) = vS;
        }
    }
    __syncthreads();

    layer_pass<true >(W1h, b1, Als, wv, lane);
    layer_pass<false>(W2h, b2, Als, wv, lane);

    // ---- final: partial dots over this wave's k-slabs (kb = 2wv, 2wv+1) ----
    {
        float u = 0.f, lap = 0.f;
        #pragma unroll
        for (int t = 0; t < 2; ++t) {
            const int kb = wv * 2 + t;
            const int k = kb * 32 + quad * 8;
            f32x4 wa = *(const f32x4*)&W3[k], wb = *(const f32x4*)&W3[k + 4];
            half8 hh = *(const half8*)(Als + (0 * 16 + kb) * SLAB + lane * 8);
            half8 ss = *(const half8*)(Als + (3 * 16 + kb) * SLAB + lane * 8);
            #pragma unroll
            for (int e = 0; e < 4; ++e) {
                u   += (float)hh[e] * wa[e] + (float)hh[e + 4] * wb[e];
                lap += (float)ss[e] * wa[e] + (float)ss[e + 4] * wb[e];
            }
        }
        // reduce over quad (lanes sharing l15): xor 16, 32
        u   += __shfl_xor(u, 16);   u   += __shfl_xor(u, 32);
        lap += __shfl_xor(lap, 16); lap += __shfl_xor(lap, 32);
        if (lane < 16) { scU[wv][l15] = u; scL[wv][l15] = lap; }
    }
    __syncthreads();

    // per-point losses
    if (tid < 16) {
        const int p = tid;
        float u = 0.f, lap = 0.f;
        #pragma unroll
        for (int w = 0; w < 8; ++w) { u += scU[w][p]; lap += scL[w][p]; }
        int gp = p0 + p;
        float vi = 0.f, vb = 0.f;
        if (gp < NI) {
            const float PIf = 3.14159265358979323846f;
            float xx = x_int[2 * gp], yy = x_int[2 * gp + 1];
            float sx = sinf(PIf * xx);
            float y2 = yy * yy;
            float sy = sinf(PIf * y2), cy = cosf(PIf * y2);
            float f = -PIf * PIf * (1.f + 4.f * y2) * sx * sy + 2.f * PIf * sx * cy;
            float r = lap - f;
            vi = r * r;
        } else if (gp < NT) {
            float uu = u + b3[0];
            vb = uu * uu;
        }
        sc[p * 2] = vi; sc[p * 2 + 1] = vb;
    }
    __syncthreads();
    if (tid == 0) {
        float svi = 0.f, svb = 0.f;
        #pragma unroll
        for (int p = 0; p < PPB; ++p) { svi += sc[p * 2]; svb += sc[p * 2 + 1]; }
        partials[blockIdx.x] = svi;
        partials[nblk + blockIdx.x] = svb;
        __threadfence();                              // release partials
        unsigned old = atomicAdd(counter, 1u);
        lastFlag = (old == (unsigned)(nblk - 1));
    }
    __syncthreads();

    // last arriving block: deterministic final reduction
    if (lastFlag) {
        __threadfence();                              // acquire partials
        if (tid < 256) {
            float si = 0.f, sb = 0.f;
            for (int i = tid; i < nblk; i += 256) {
                si += partials[i];
                sb += partials[nblk + i];
            }
            #pragma unroll
            for (int off = 32; off > 0; off >>= 1) {
                si += __shfl_xor(si, off);
                sb += __shfl_xor(sb, off);
            }
            int w = tid >> 6;
            if ((tid & 63) == 0) { ri[w] = si; rb[w] = sb; }
        }
    }
    __syncthreads();
    if (lastFlag && tid == 0) {
        float inter = (ri[0] + ri[1] + ri[2] + ri[3]) / (float)NI;
        float bound = (rb[0] + rb[1] + rb[2] + rb[3]) / (float)(NT - NI);
        out[0] = 0.01f * inter + bound;   // ALPHA = 0.01
        out[1] = inter;
        out[2] = bound;
    }
}

// ---------------------------------------------------------------------------
extern "C" void kernel_launch(void* const* d_in, const int* in_sizes, int n_in,
                              void* d_out, int out_size, void* d_ws, size_t ws_size,
                              hipStream_t stream)
{
    const float* x_int = (const float*)d_in[0];
    const float* x_bnd = (const float*)d_in[1];
    const float* W0 = (const float*)d_in[2];
    const float* b0 = (const float*)d_in[3];
    const float* W1 = (const float*)d_in[4];
    const float* b1 = (const float*)d_in[5];
    const float* W2 = (const float*)d_in[6];
    const float* b2 = (const float*)d_in[7];
    const float* W3 = (const float*)d_in[8];
    const float* b3 = (const float*)d_in[9];

    int NI = in_sizes[0] / 2;    // 20000
    int NB = in_sizes[1] / 2;    // 800
    int NT = NI + NB;            // 20800
    int nblk = (NT + PPB - 1) / PPB;   // 1300
    (void)NB;

    // ws: [partials 10.4KB][counter @12KB][pad to 16KB][W1h 512KB][W2h 512KB]
    float* partials = (float*)d_ws;
    unsigned* counter = (unsigned*)((char*)d_ws + 12288);
    _Float16* W1h = (_Float16*)((char*)d_ws + 16384);
    _Float16* W2h = W1h + 262144;

    prep_wt<<<128, 256, 0, stream>>>(W1, W2, W1h, W2h, counter);

    pois_fused<<<nblk, 512, 0, stream>>>(
        x_int, x_bnd, W0, b0, W1h, b1, W2h, b2, W3, b3,
        partials, counter, (float*)d_out, NI, NT, nblk);
}

// Round 3
// 193.619 us; speedup vs baseline: 1.0749x; 1.0711x over previous
//
#include <hip/hip_runtime.h>
#include <math.h>

#define HID 512
#define PPB 16              // points per block (one 16-p MFMA column)
#define SLAB 512            // halfs per slab: 16 p x 32 k, 1 KB, lane-linear

typedef __attribute__((ext_vector_type(8))) _Float16 half8;   // 4 VGPRs, MFMA frag
typedef __attribute__((ext_vector_type(4))) _Float16 half4;
typedef __attribute__((ext_vector_type(4))) float f32x4;

static __device__ __forceinline__ float fast_tanh(float x) {
    float e = __expf(2.f * x);
    return 1.f - 2.f / (e + 1.f);
}

// ---------------------------------------------------------------------------
// Slab element order (lane-linear): element (p_local, k_local=quad*8+e) sits
// at halfs-offset lane*8+e, lane = quad*16 + p_local. One wave b128 access at
// lane*8 = contiguous 1 KB: conflict-free in LDS, coalesced in global.
// A slabs: index s*16 + kb   (s = state, kb = k/32). 64 KB total -> 2 blk/CU.
// W slabs: index jb*16 + kb  (jb = j/16). 512 KB per layer.
// ---------------------------------------------------------------------------

__global__ __launch_bounds__(256) void prep_wt(
    const float* __restrict__ W1, const float* __restrict__ W2,
    _Float16* __restrict__ W1h, _Float16* __restrict__ W2h,
    unsigned* __restrict__ counter)
{
    if (blockIdx.x == 0 && threadIdx.x == 0) *counter = 0u;   // reset per replay
    __shared__ float T[64][65];
    int b = blockIdx.x;
    const float* W = (b < 64) ? W1 : W2;
    _Float16* Wh   = (b < 64) ? W1h : W2h;
    int tb = b & 63;
    int jbG = tb >> 3, kbG = tb & 7;
    int j0 = jbG * 64, k0 = kbG * 64;
    int t = threadIdx.x;
    #pragma unroll
    for (int r = 0; r < 16; ++r) {
        int kl = r * 4 + (t >> 6);
        int jl = t & 63;
        T[kl][jl] = W[(size_t)(k0 + kl) * HID + j0 + jl];   // coalesced
    }
    __syncthreads();
    int ljb = t >> 6;                  // local 16-j group (0..3)
    int l15 = (t >> 2) & 15;           // j within group
    int quad = t & 3;                  // k octet
    #pragma unroll
    for (int lkb = 0; lkb < 2; ++lkb) {
        half8 v;
        #pragma unroll
        for (int k8 = 0; k8 < 8; ++k8)
            v[k8] = (_Float16)T[lkb * 32 + quad * 8 + k8][ljb * 16 + l15];
        size_t out = (size_t)((jbG * 4 + ljb) * 16 + (kbG * 2 + lkb)) * SLAB
                   + (quad * 16 + l15) * 8;
        *(half8*)(Wh + out) = v;
    }
}

// ---------------------------------------------------------------------------
// One hidden-layer pass. A (B-op) in LDS slabs; W (A-op) streamed from L2
// with ping-pong register prefetch. Wave wv (of 8) owns j in [64wv, 64wv+64).
// NEW (R3): A reads are software-pipelined IN PLACE — a[s] for kb+1 is
// reloaded into the same registers right after the 4 MFMAs consuming a[s]
// for kb (WAR-pinned; zero extra VGPRs). Removes the per-iter
// ds_read -> lgkmcnt(0) -> MFMA load-to-use stall.
// ---------------------------------------------------------------------------
template<bool FULL>
static __device__ __forceinline__ void layer_pass(
    const _Float16* __restrict__ Wh, const float* __restrict__ bias,
    _Float16* Als, int wv, int lane)
{
    const int l15 = lane & 15, quad = lane >> 4;
    const int jb0 = wv * 4;                 // first 16-j W slab index
    const int loff = lane * 8;              // lane-linear frag offset (halfs)

    f32x4 acc[4][4];                        // [state][jt]
    #pragma unroll
    for (int s = 0; s < 4; ++s)
        #pragma unroll
        for (int jt = 0; jt < 4; ++jt) acc[s][jt] = (f32x4)0.f;

    half8 wA[4], wB[4];
    #pragma unroll
    for (int jt = 0; jt < 4; ++jt)
        wA[jt] = *(const half8*)(Wh + (size_t)((jb0 + jt) * 16) * SLAB + loff);

    half8 a[4];                             // A frags, pipelined in place
    #pragma unroll
    for (int s = 0; s < 4; ++s)
        a[s] = *(const half8*)(Als + (s * 16 + 0) * SLAB + loff);

    auto iter = [&](int kb, half8 (&wc)[4], half8 (&wn)[4]) {
        // W prefetch for kb+1 (depth 1; covered by slack + TLP)
        if (kb < 15) {
            #pragma unroll
            for (int jt = 0; jt < 4; ++jt)
                wn[jt] = *(const half8*)(Wh + (size_t)((jb0 + jt) * 16 + kb + 1) * SLAB + loff);
        }
        #pragma unroll
        for (int s = 0; s < 4; ++s) {
            #pragma unroll
            for (int jt = 0; jt < 4; ++jt)
                acc[s][jt] = __builtin_amdgcn_mfma_f32_16x16x32_f16(
                    wc[jt], a[s], acc[s][jt], 0, 0, 0);
            // reload a[s] for kb+1 right after its last use for kb
            if (kb < 15)
                a[s] = *(const half8*)(Als + (s * 16 + kb + 1) * SLAB + loff);
        }
    };

    #pragma unroll
    for (int kb = 0; kb < 16; kb += 2) {
        iter(kb,     wA, wB);
        iter(kb + 1, wB, wA);
    }

    __syncthreads();   // all waves done reading Als; safe to overwrite

    // epilogue: D row m = jt*16+quad*4+r (j-offset jbase), col p = l15.
    // Next-layer slab for jbase is kb' = jbase>>5 = 2wv + (jt>>1);
    // k_local = (jt&1)*16 + quad*4 + r.
    #pragma unroll
    for (int jt = 0; jt < 4; ++jt) {
        const int jbase = wv * 64 + jt * 16 + quad * 4;
        const int kbp = wv * 2 + (jt >> 1);
        const int qo = (jt & 1) * 2 + (quad >> 1);
        const int e0 = (quad & 1) * 4;
        f32x4 bv = *(const f32x4*)&bias[jbase];
        half4 vh, vt1, vt2, vS;
        #pragma unroll
        for (int r = 0; r < 4; ++r) {
            float a_  = fast_tanh(acc[0][jt][r] + bv[r]);
            float g  = 1.f - a_ * a_;
            float z1 = acc[1][jt][r];
            float z2 = acc[2][jt][r];
            vh[r] = (_Float16)a_;
            if (FULL) {
                vt1[r] = (_Float16)(g * z1);
                vt2[r] = (_Float16)(g * z2);
            }
            vS[r] = (_Float16)(g * acc[3][jt][r] - 2.f * a_ * g * (z1 * z1 + z2 * z2));
        }
        const int ooff = (qo * 16 + l15) * 8 + e0;
        *(half4*)(Als + (0 * 16 + kbp) * SLAB + ooff) = vh;
        if (FULL) {
            *(half4*)(Als + (1 * 16 + kbp) * SLAB + ooff) = vt1;
            *(half4*)(Als + (2 * 16 + kbp) * SLAB + ooff) = vt2;
        }
        *(half4*)(Als + (3 * 16 + kbp) * SLAB + ooff) = vS;
    }
    __syncthreads();   // Als(next layer) complete
}

// ---------------------------------------------------------------------------
// Fused: layer0 init -> L1 -> L2 -> final dot + loss partials + grid reduce.
// 16 pts/block, 512 threads (8 waves), 64 KB LDS -> 2 blocks/CU.
// ---------------------------------------------------------------------------
__global__ __launch_bounds__(512, 4) void pois_fused(
    const float* __restrict__ x_int, const float* __restrict__ x_bnd,
    const float* __restrict__ W0, const float* __restrict__ b0,
    const _Float16* __restrict__ W1h, const float* __restrict__ b1,
    const _Float16* __restrict__ W2h, const float* __restrict__ b2,
    const float* __restrict__ W3, const float* __restrict__ b3,
    float* __restrict__ partials, unsigned* __restrict__ counter,
    float* __restrict__ out, int NI, int NT, int nblk)
{
    __shared__ _Float16 Als[4 * 16 * SLAB];   // 64 KB
    __shared__ float scU[8][16], scL[8][16], sc[32];
    __shared__ float ri[4], rb[4];
    __shared__ int lastFlag;

    const int tid = threadIdx.x;
    const int wv = tid >> 6, lane = tid & 63;
    const int l15 = lane & 15, quad = lane >> 4;
    const int p0 = blockIdx.x * PPB;

    // ---- layer 0: wave wv fills slabs kb = 2wv, 2wv+1 ----
    {
        int gp = p0 + l15;
        int gpc = (gp >= NT) ? 0 : gp;
        float xx, yy;
        if (gpc < NI) { xx = x_int[2 * gpc];        yy = x_int[2 * gpc + 1]; }
        else          { xx = x_bnd[2 * (gpc - NI)]; yy = x_bnd[2 * (gpc - NI) + 1]; }
        #pragma unroll
        for (int t = 0; t < 2; ++t) {
            const int kb = wv * 2 + t;
            const int k = kb * 32 + quad * 8;
            f32x4 w0a = *(const f32x4*)&W0[k],       w0b = *(const f32x4*)&W0[k + 4];
            f32x4 w1a = *(const f32x4*)&W0[HID + k], w1b = *(const f32x4*)&W0[HID + k + 4];
            f32x4 b0a = *(const f32x4*)&b0[k],       b0b = *(const f32x4*)&b0[k + 4];
            half8 vh, vt1, vt2, vS;
            #pragma unroll
            for (int e = 0; e < 8; ++e) {
                float w0i = (e < 4) ? w0a[e] : w0b[e - 4];
                float w1i = (e < 4) ? w1a[e] : w1b[e - 4];
                float bbi = (e < 4) ? b0a[e] : b0b[e - 4];
                float a = fast_tanh(xx * w0i + yy * w1i + bbi);
                float g = 1.f - a * a;
                vh[e]  = (_Float16)a;
                vt1[e] = (_Float16)(g * w0i);
                vt2[e] = (_Float16)(g * w1i);
                vS[e]  = (_Float16)(-2.f * a * g * (w0i * w0i + w1i * w1i));
            }
            const int off = lane * 8;
            *(half8*)(Als + (0 * 16 + kb) * SLAB + off) = vh;
            *(half8*)(Als + (1 * 16 + kb) * SLAB + off) = vt1;
            *(half8*)(Als + (2 * 16 + kb) * SLAB + off) = vt2;
            *(half8*)(Als + (3 * 16 + kb) * SLAB + off) = vS;
        }
    }
    __syncthreads();

    layer_pass<true >(W1h, b1, Als, wv, lane);
    layer_pass<false>(W2h, b2, Als, wv, lane);

    // ---- final: partial dots over this wave's k-slabs (kb = 2wv, 2wv+1) ----
    {
        float u = 0.f, lap = 0.f;
        #pragma unroll
        for (int t = 0; t < 2; ++t) {
            const int kb = wv * 2 + t;
            const int k = kb * 32 + quad * 8;
            f32x4 wa = *(const f32x4*)&W3[k], wb = *(const f32x4*)&W3[k + 4];
            half8 hh = *(const half8*)(Als + (0 * 16 + kb) * SLAB + lane * 8);
            half8 ss = *(const half8*)(Als + (3 * 16 + kb) * SLAB + lane * 8);
            #pragma unroll
            for (int e = 0; e < 4; ++e) {
                u   += (float)hh[e] * wa[e] + (float)hh[e + 4] * wb[e];
                lap += (float)ss[e] * wa[e] + (float)ss[e + 4] * wb[e];
            }
        }
        // reduce over quad (lanes sharing l15): xor 16, 32
        u   += __shfl_xor(u, 16);   u   += __shfl_xor(u, 32);
        lap += __shfl_xor(lap, 16); lap += __shfl_xor(lap, 32);
        if (lane < 16) { scU[wv][l15] = u; scL[wv][l15] = lap; }
    }
    __syncthreads();

    // per-point losses
    if (tid < 16) {
        const int p = tid;
        float u = 0.f, lap = 0.f;
        #pragma unroll
        for (int w = 0; w < 8; ++w) { u += scU[w][p]; lap += scL[w][p]; }
        int gp = p0 + p;
        float vi = 0.f, vb = 0.f;
        if (gp < NI) {
            const float PIf = 3.14159265358979323846f;
            float xx = x_int[2 * gp], yy = x_int[2 * gp + 1];
            float sx = sinf(PIf * xx);
            float y2 = yy * yy;
            float sy = sinf(PIf * y2), cy = cosf(PIf * y2);
            float f = -PIf * PIf * (1.f + 4.f * y2) * sx * sy + 2.f * PIf * sx * cy;
            float r = lap - f;
            vi = r * r;
        } else if (gp < NT) {
            float uu = u + b3[0];
            vb = uu * uu;
        }
        sc[p * 2] = vi; sc[p * 2 + 1] = vb;
    }
    __syncthreads();
    if (tid == 0) {
        float svi = 0.f, svb = 0.f;
        #pragma unroll
        for (int p = 0; p < PPB; ++p) { svi += sc[p * 2]; svb += sc[p * 2 + 1]; }
        partials[blockIdx.x] = svi;
        partials[nblk + blockIdx.x] = svb;
        __threadfence();                              // release partials
        unsigned old = atomicAdd(counter, 1u);
        lastFlag = (old == (unsigned)(nblk - 1));
    }
    __syncthreads();

    // last arriving block: deterministic final reduction
    if (lastFlag) {
        __threadfence();                              // acquire partials
        if (tid < 256) {
            float si = 0.f, sb = 0.f;
            for (int i = tid; i < nblk; i += 256) {
                si += partials[i];
                sb += partials[nblk + i];
            }
            #pragma unroll
            for (int off = 32; off > 0; off >>= 1) {
                si += __shfl_xor(si, off);
                sb += __shfl_xor(sb, off);
            }
            int w = tid >> 6;
            if ((tid & 63) == 0) { ri[w] = si; rb[w] = sb; }
        }
    }
    __syncthreads();
    if (lastFlag && tid == 0) {
        float inter = (ri[0] + ri[1] + ri[2] + ri[3]) / (float)NI;
        float bound = (rb[0] + rb[1] + rb[2] + rb[3]) / (float)(NT - NI);
        out[0] = 0.01f * inter + bound;   // ALPHA = 0.01
        out[1] = inter;
        out[2] = bound;
    }
}

// ---------------------------------------------------------------------------
extern "C" void kernel_launch(void* const* d_in, const int* in_sizes, int n_in,
                              void* d_out, int out_size, void* d_ws, size_t ws_size,
                              hipStream_t stream)
{
    const float* x_int = (const float*)d_in[0];
    const float* x_bnd = (const float*)d_in[1];
    const float* W0 = (const float*)d_in[2];
    const float* b0 = (const float*)d_in[3];
    const float* W1 = (const float*)d_in[4];
    const float* b1 = (const float*)d_in[5];
    const float* W2 = (const float*)d_in[6];
    const float* b2 = (const float*)d_in[7];
    const float* W3 = (const float*)d_in[8];
    const float* b3 = (const float*)d_in[9];

    int NI = in_sizes[0] / 2;    // 20000
    int NB = in_sizes[1] / 2;    // 800
    int NT = NI + NB;            // 20800
    int nblk = (NT + PPB - 1) / PPB;   // 1300
    (void)NB;

    // ws: [partials 10.4KB][counter @12KB][pad to 16KB][W1h 512KB][W2h 512KB]
    float* partials = (float*)d_ws;
    unsigned* counter = (unsigned*)((char*)d_ws + 12288);
    _Float16* W1h = (_Float16*)((char*)d_ws + 16384);
    _Float16* W2h = W1h + 262144;

    prep_wt<<<128, 256, 0, stream>>>(W1, W2, W1h, W2h, counter);

    pois_fused<<<nblk, 512, 0, stream>>>(
        x_int, x_bnd, W0, b0, W1h, b1, W2h, b2, W3, b3,
        partials, counter, (float*)d_out, NI, NT, nblk);
}